// Round 20
// baseline (263.605 us; speedup 1.0000x reference)
//
#include <hip/hip_runtime.h>
#include <math.h>

typedef __attribute__((ext_vector_type(8))) short short8;
typedef __attribute__((ext_vector_type(4))) float v4f;
typedef __attribute__((ext_vector_type(4))) unsigned short us4;

#define INV_SCALE 0.07216878364870322f  // 1/sqrt(64*3)

__device__ __forceinline__ unsigned short f2bf(float f) {
  unsigned u = __builtin_bit_cast(unsigned, f);
  u = (u + 0x7FFFu + ((u >> 16) & 1u)) >> 16;  // RNE
  return (unsigned short)u;
}
__device__ __forceinline__ float bf2f(unsigned short h) {
  unsigned u = ((unsigned)h) << 16;
  return __builtin_bit_cast(float, u);
}

enum { OM_PLAIN = 0, OM_Q = 1, OM_K = 2, OM_VT = 3, OM_PK = 4, OM_PQ = 5 };

// -----------------------------------------------------------------------------
// ROUND-17 RESUBMIT x3 (R17/R18/R19 were broker timeouts; NP=6 never ran).
// R16 structure (257.3 us, best) + NP=3 -> NP=6 panel loops.
// R16 calibrated the boundary model: fixed harness/launch floor ~82 us,
// per-boundary ~5 us; real prep/proj/out work ~34 us. proj_all at NP=3 ran
// 816 working blocks at 3 blocks/CU = TWO residency rounds (tail round 48
// blocks at 6% occupancy) and loaded each A-slab twice. NP=6: 408 working
// blocks -> single round, A-frag loads halved, loop overhead amortized.
// out_gemm likewise 256 -> 128 blocks. attn_fused untouched.
// -----------------------------------------------------------------------------
// prep_all grid: 1896 blocks. bid < 1680: x/re -> bf16 (8 elems/thread).
// bid >= 1680: weight transpose tile (6 mats x 36 tiles).
__global__ __launch_bounds__(256) void prep_all(
    const float* __restrict__ x, const float* __restrict__ re,
    const float* __restrict__ Wq, const float* __restrict__ Wk,
    const float* __restrict__ Wv, const float* __restrict__ Wpk,
    const float* __restrict__ Wpq, const float* __restrict__ Wo,
    unsigned short* __restrict__ xb, unsigned short* __restrict__ reb,
    unsigned short* __restrict__ Wt) {
  __shared__ unsigned short Ts[64][68];
  const int bid = blockIdx.x;
  const int t = threadIdx.x;
  if (bid < 1680) {
    size_t idx = ((size_t)bid * 256 + t) * 8;
    const float* src;
    unsigned short* dst;
    if (idx < 3145728) {
      src = x + idx; dst = xb + idx;
    } else {
      size_t r = idx - 3145728;
      if (r >= 294912) return;
      src = re + r; dst = reb + r;
    }
    float4 u0 = *(const float4*)src;
    float4 u1 = *(const float4*)(src + 4);
    short8 v;
    v[0] = (short)f2bf(u0.x); v[1] = (short)f2bf(u0.y);
    v[2] = (short)f2bf(u0.z); v[3] = (short)f2bf(u0.w);
    v[4] = (short)f2bf(u1.x); v[5] = (short)f2bf(u1.y);
    v[6] = (short)f2bf(u1.z); v[7] = (short)f2bf(u1.w);
    *(short8*)dst = v;
    return;
  }
  // weight transpose: 384x384 fp32 [k][n] -> bf16 [n][k]
  const int wb = bid - 1680;
  const int mat = wb / 36, rem = wb % 36;
  const float* W = mat == 0 ? Wq : mat == 1 ? Wk : mat == 2 ? Wv
                 : mat == 3 ? Wpk : mat == 4 ? Wpq : Wo;
  const int tk = (rem % 6) * 64, tn = (rem / 6) * 64;
#pragma unroll
  for (int it = 0; it < 4; ++it) {
    int r = (t >> 4) + it * 16, c = (t & 15) * 4;
    float4 v = *(const float4*)(W + (size_t)(tk + r) * 384 + tn + c);
    us4 p = {f2bf(v.x), f2bf(v.y), f2bf(v.z), f2bf(v.w)};
    *(us4*)&Ts[r][c] = p;
  }
  __syncthreads();
  unsigned short* outp = Wt + (size_t)mat * 147456;
#pragma unroll
  for (int it = 0; it < 2; ++it) {
    int n = (t >> 3) + it * 32, kc = (t & 7) * 8;
    unsigned short tmp[8];
#pragma unroll
    for (int j = 0; j < 8; ++j) tmp[j] = Ts[kc + j][n];
    *(short8*)(outp + (size_t)(tn + n) * 384 + tk + kc) = *(short8*)tmp;
  }
}

// -----------------------------------------------------------------------------
// GEMM body (R9 panel-loop): A-frags (bf16) loaded ONCE per block into
// registers; loop NP n-panels restaging only B (L2-resident Wt).
// -----------------------------------------------------------------------------
template <int OMODE, int NP>
__device__ __forceinline__ void pgemm_body(
    const unsigned short* __restrict__ A, const unsigned short* __restrict__ Bt,
    const float* __restrict__ bias, void* __restrict__ out,
    int m0, int ng0, float scale, unsigned short (*Bs)[392]) {
  const int t = threadIdx.x;
  const int lane = t & 63, w = t >> 6, li = lane & 15, quad = lane >> 4;
  const int row = m0 + w * 16 + li;
  const int sr = t >> 2, scq = (t & 3) * 96;

#pragma unroll
  for (int i = 0; i < 12; ++i)
    *(short8*)&Bs[sr][scq + i * 8] =
        *(const short8*)(Bt + (size_t)(ng0 * 64 + sr) * 384 + scq + i * 8);

  short8 afr[12];
#pragma unroll
  for (int kk = 0; kk < 12; ++kk)
    afr[kk] = *(const short8*)(A + (size_t)row * 384 + kk * 32 + quad * 8);

#pragma unroll
  for (int pp = 0; pp < NP; ++pp) {
    __syncthreads();  // stage of panel pp visible
    v4f acc[4] = {};
#pragma unroll
    for (int kk = 0; kk < 12; ++kk) {
#pragma unroll
      for (int nt = 0; nt < 4; ++nt) {
        short8 bf = *(const short8*)&Bs[nt * 16 + li][kk * 32 + quad * 8];
        acc[nt] = __builtin_amdgcn_mfma_f32_16x16x32_bf16(afr[kk], bf, acc[nt], 0, 0, 0);
      }
    }
    __syncthreads();  // all Bs reads done; free for restage
    if (pp + 1 < NP) {
#pragma unroll
      for (int i = 0; i < 12; ++i)
        *(short8*)&Bs[sr][scq + i * 8] =
            *(const short8*)(Bt + (size_t)((ng0 + pp + 1) * 64 + sr) * 384 + scq + i * 8);
    }
    const int n0 = (ng0 + pp) * 64;
#pragma unroll
    for (int nt = 0; nt < 4; ++nt) {
      int col = n0 + nt * 16 + li;
      float bv = bias[col];
      int h = col >> 6, d = col & 63;
#pragma unroll
      for (int i = 0; i < 4; ++i) {
        int orow = m0 + w * 16 + quad * 4 + i;
        float val = (acc[nt][i] + bv) * scale;
        if constexpr (OMODE == OM_PLAIN) {
          ((float*)out)[(size_t)orow * 384 + col] = val;
        } else if constexpr (OMODE == OM_Q || OMODE == OM_K) {
          int b = orow >> 10, n = orow & 1023;
          ((unsigned short*)out)[((size_t)(b * 6 + h) << 16) + (n << 6) + d] = f2bf(val);
        } else if constexpr (OMODE == OM_VT) {
          int b = orow >> 10, n = orow & 1023;
          ((unsigned short*)out)[((size_t)(b * 6 + h) << 16) + (d << 10) + n] = f2bf(val);
        } else {  // OM_PK / OM_PQ: [h][p][d]
          ((unsigned short*)out)[(size_t)h * 49152 + (size_t)orow * 64 + d] = f2bf(val);
        }
      }
    }
  }
}

// Grid (128, 4): y<3 -> which=y (q/k/v), NP=6 full width, M=8192.
// y==3 -> bx<12: pk (m0=bx*64); 12<=bx<24: pq (m0=(bx-12)*64); else no-op.
// 408 working blocks <= 768 co-residency slots -> single residency round.
__global__ __launch_bounds__(256, 3) void proj_all(
    const unsigned short* __restrict__ xb, const unsigned short* __restrict__ reb,
    const unsigned short* __restrict__ Wt,
    const float* __restrict__ bq, const float* __restrict__ bk,
    const float* __restrict__ bv, const float* __restrict__ bpk,
    const float* __restrict__ bpq,
    unsigned short* __restrict__ qw, unsigned short* __restrict__ kw,
    unsigned short* __restrict__ vtw, unsigned short* __restrict__ pkw,
    unsigned short* __restrict__ pqw) {
  __shared__ __align__(16) unsigned short Bs[64][392];
  const int y = blockIdx.y;
  const int bx = blockIdx.x;
  if (y < 3) {
    const int m0 = bx * 64;
    const unsigned short* Bt = Wt + (size_t)y * 147456;
    switch (y) {
      case 0: pgemm_body<OM_Q, 6>(xb, Bt, bq, qw,  m0, 0, INV_SCALE, Bs); break;
      case 1: pgemm_body<OM_K, 6>(xb, Bt, bk, kw,  m0, 0, 1.f, Bs); break;
      default: pgemm_body<OM_VT,6>(xb, Bt, bv, vtw, m0, 0, 1.f, Bs); break;
    }
  } else {
    if (bx < 12)
      pgemm_body<OM_PK, 6>(reb, Wt + 3 * 147456, bpk, pkw, bx * 64, 0, 1.f, Bs);
    else if (bx < 24)
      pgemm_body<OM_PQ, 6>(reb, Wt + 4 * 147456, bpq, pqw, (bx - 12) * 64, 0, INV_SCALE, Bs);
  }
}

// Grid (128): NP=6 full width; 128 blocks, single residency round.
__global__ __launch_bounds__(256, 3) void out_gemm(
    const unsigned short* __restrict__ ao, const unsigned short* __restrict__ Bt,
    const float* __restrict__ bo, float* __restrict__ out) {
  __shared__ __align__(16) unsigned short Bs[64][392];
  pgemm_body<OM_PLAIN, 6>(ao, Bt, bo, out, blockIdx.x * 64, 0, 1.f, Bs);
}

// -----------------------------------------------------------------------------
// Fused disentangled attention — ROUND-8 KERNEL VERBATIM (best measured:
// 139.4-141.4 us, FETCH 14.6 MB). XCD working-set swizzle (validated: FETCH
// 60->14.6 MB) + T14 stage split on the 146 us ROUND-4 structure (ASTR=72,
// LDS band staging, 4 barriers, register-lean). Do not touch.
// -----------------------------------------------------------------------------
#define ASTR 72  // LDS row stride in shorts (144 B): 16B-aligned, 2-way-free banks

__global__ __launch_bounds__(256, 3) void attn_fused(
    const unsigned short* __restrict__ q, const unsigned short* __restrict__ k,
    const unsigned short* __restrict__ vt, const unsigned short* __restrict__ pk,
    const unsigned short* __restrict__ pq, unsigned short* __restrict__ ao) {
  __shared__ __align__(16) unsigned short band1[128][ASTR];  // pk band, then T1^T
  __shared__ __align__(16) unsigned short band2[128][ASTR];  // pq band, then T2^T
  __shared__ __align__(16) unsigned short Ps[64][ASTR];

  // XCD working-set remap: flat id -> (bh, n0) so each XCD owns 6 bh.
  const int f = blockIdx.x + (blockIdx.y << 4);  // hw linear id, 0..767
  const int g = f & 7, s = f >> 3;               // XCD group, slot
  const int bh = g * 6 + (s >> 4);
  const int n0 = (s & 15) * 64;
  const int h = bh % 6, b = bh / 6;
  const int t = threadIdx.x;
  const int lane = t & 63, w = t >> 6;
  const int li = lane & 15, quad = lane >> 4;

  const unsigned short* qb = q + ((size_t)bh << 16);
  const unsigned short* kb = k + ((size_t)bh << 16);
  const unsigned short* vb = vt + ((size_t)bh << 16);
  const unsigned short* pkh = pk + (size_t)h * 49152;
  const unsigned short* pqh = pq + (size_t)h * 49152;

  // q A-frags: loaded once (q pre-scaled by INV_SCALE)
  short8 aq0 = *(const short8*)(qb + (size_t)(n0 + w * 16 + li) * 64 + quad * 8);
  short8 aq1 = *(const short8*)(qb + (size_t)(n0 + w * 16 + li) * 64 + 32 + quad * 8);

  float l_part[4] = {0.f, 0.f, 0.f, 0.f};
  v4f o[4] = {};

  // T14 stage split: per-thread staging slice (row sr, 32-short quarter sc).
  const int sr = t >> 1, sc = (t & 1) * 32;
  short8 st1[4], st2[4];
  {
    int src = n0 - 0 - 63 + 384 + sr;
    src = src < 0 ? 0 : (src > 767 ? 767 : src);
    const unsigned short* p1 = pkh + (size_t)src * 64 + sc;
    const unsigned short* p2 = pqh + (size_t)src * 64 + sc;
#pragma unroll
    for (int ss = 0; ss < 4; ++ss) {
      st1[ss] = *(const short8*)(p1 + ss * 8);
      st2[ss] = *(const short8*)(p2 + ss * 8);
    }
  }

  for (int j0 = 0; j0 < 1024; j0 += 64) {
    __syncthreads();  // S0: prev gather reads done; band buffers free
    // ---- write pre-fetched pos bands to LDS ----
#pragma unroll
    for (int ss = 0; ss < 4; ++ss) {
      *(short8*)&band1[sr][sc + ss * 8] = st1[ss];
      *(short8*)&band2[sr][sc + ss * 8] = st2[ss];
    }
    __syncthreads();  // S1: bands visible

    // ---- issue next tile's stage loads (consumed at next S0) ----
    {
      int src = n0 - (j0 + 64) - 63 + 384 + sr;  // last iter: clamped, unused
      src = src < 0 ? 0 : (src > 767 ? 767 : src);
      const unsigned short* p1 = pkh + (size_t)src * 64 + sc;
      const unsigned short* p2 = pqh + (size_t)src * 64 + sc;
#pragma unroll
      for (int ss = 0; ss < 4; ++ss) {
        st1[ss] = *(const short8*)(p1 + ss * 8);
        st2[ss] = *(const short8*)(p2 + ss * 8);
      }
    }

    // k A-frags for T2 (rows j0 + w*16 + li)
    short8 ak0 = *(const short8*)(kb + (size_t)(j0 + w * 16 + li) * 64 + quad * 8);
    short8 ak1 = *(const short8*)(kb + (size_t)(j0 + w * 16 + li) * 64 + 32 + quad * 8);

    // ---- T1 = q' @ pkband^T, T2 = k @ pq'band^T (B-frags from LDS) ----
    v4f t1a[8] = {}, t2a[8] = {};
#pragma unroll
    for (int ct = 0; ct < 8; ++ct) {
      short8 b10 = *(const short8*)&band1[ct * 16 + li][quad * 8];
      short8 b11 = *(const short8*)&band1[ct * 16 + li][32 + quad * 8];
      t1a[ct] = __builtin_amdgcn_mfma_f32_16x16x32_bf16(aq0, b10, t1a[ct], 0, 0, 0);
      t1a[ct] = __builtin_amdgcn_mfma_f32_16x16x32_bf16(aq1, b11, t1a[ct], 0, 0, 0);
      short8 b20 = *(const short8*)&band2[ct * 16 + li][quad * 8];
      short8 b21 = *(const short8*)&band2[ct * 16 + li][32 + quad * 8];
      t2a[ct] = __builtin_amdgcn_mfma_f32_16x16x32_bf16(ak0, b20, t2a[ct], 0, 0, 0);
      t2a[ct] = __builtin_amdgcn_mfma_f32_16x16x32_bf16(ak1, b21, t2a[ct], 0, 0, 0);
    }
    __syncthreads();  // S2: all band B-frag reads complete before overwrite

    // ---- write T1^T/T2^T into the (dead) band buffers ----
#pragma unroll
    for (int ct = 0; ct < 8; ++ct) {
      us4 p1 = {f2bf(t1a[ct][0]), f2bf(t1a[ct][1]), f2bf(t1a[ct][2]), f2bf(t1a[ct][3])};
      us4 p2 = {f2bf(t2a[ct][0]), f2bf(t2a[ct][1]), f2bf(t2a[ct][2]), f2bf(t2a[ct][3])};
      *(us4*)&band1[ct * 16 + li][w * 16 + quad * 4] = p1;
      *(us4*)&band2[ct * 16 + li][w * 16 + quad * 4] = p2;
    }
    // ---- S_qk (B-frags = k rows direct from global/L1) ----
    v4f sqk[4] = {};
#pragma unroll
    for (int nt = 0; nt < 4; ++nt) {
      short8 b0 = *(const short8*)(kb + (size_t)(j0 + nt * 16 + li) * 64 + quad * 8);
      short8 b1 = *(const short8*)(kb + (size_t)(j0 + nt * 16 + li) * 64 + 32 + quad * 8);
      sqk[nt] = __builtin_amdgcn_mfma_f32_16x16x32_bf16(aq0, b0, sqk[nt], 0, 0, 0);
      sqk[nt] = __builtin_amdgcn_mfma_f32_16x16x32_bf16(aq1, b1, sqk[nt], 0, 0, 0);
    }
    __syncthreads();  // S3: T^T visible cross-wave

    // ---- gather + exp (scale pre-folded) + Ps ----
#pragma unroll
    for (int nt = 0; nt < 4; ++nt) {
      int jl = nt * 16 + li;
#pragma unroll
      for (int i = 0; i < 4; ++i) {
        int nl = w * 16 + quad * 4 + i;
        int r = nl - jl + 63;
        float s2 = sqk[nt][i] + bf2f(band1[r][nl]) + bf2f(band2[r][jl]);
        float p = __expf(s2);
        l_part[i] += p;
        Ps[nl][jl] = f2bf(p);
      }
    }
    // ---- PV (A-frag Ps: same-wave rows; B-frag vt direct from global) ----
#pragma unroll
    for (int kst = 0; kst < 2; ++kst) {
      short8 ap = *(const short8*)&Ps[w * 16 + li][kst * 32 + quad * 8];
#pragma unroll
      for (int nt = 0; nt < 4; ++nt) {
        short8 bv2 = *(const short8*)(vb + (size_t)(nt * 16 + li) * 1024 + j0 + kst * 32 + quad * 8);
        o[nt] = __builtin_amdgcn_mfma_f32_16x16x32_bf16(ap, bv2, o[nt], 0, 0, 0);
      }
    }
  }

  // final: reduce l across the 16 col-lanes, normalize, store (B,N,C) bf16
#pragma unroll
  for (int i = 0; i < 4; ++i) {
    float l = l_part[i];
    l += __shfl_xor(l, 1);
    l += __shfl_xor(l, 2);
    l += __shfl_xor(l, 4);
    l += __shfl_xor(l, 8);
    float inv_l = 1.f / l;
    int nl = w * 16 + quad * 4 + i;
#pragma unroll
    for (int nt = 0; nt < 4; ++nt)
      ao[((size_t)(b * 1024 + n0 + nl)) * 384 + h * 64 + nt * 16 + li] =
          f2bf(o[nt][i] * inv_l);
  }
}

// -----------------------------------------------------------------------------
extern "C" void kernel_launch(void* const* d_in, const int* in_sizes, int n_in,
                              void* d_out, int out_size, void* d_ws,
                              size_t ws_size, hipStream_t stream) {
  const float* x   = (const float*)d_in[0];
  const float* re  = (const float*)d_in[2];
  const float* Wq  = (const float*)d_in[3];
  const float* bq  = (const float*)d_in[4];
  const float* Wk  = (const float*)d_in[5];
  const float* bk  = (const float*)d_in[6];
  const float* Wv  = (const float*)d_in[7];
  const float* bv  = (const float*)d_in[8];
  const float* Wpk = (const float*)d_in[9];
  const float* bpk = (const float*)d_in[10];
  const float* Wpq = (const float*)d_in[11];
  const float* bpq = (const float*)d_in[12];
  const float* Wo  = (const float*)d_in[13];
  const float* bo  = (const float*)d_in[14];
  float* out = (float*)d_out;

  unsigned short* ws = (unsigned short*)d_ws;
  unsigned short* Wt  = ws;                 // 6*384*384
  unsigned short* qw  = Wt + 884736;        // 48*1024*64 (pre-scaled)
  unsigned short* kw  = qw + 3145728;
  unsigned short* vtw = kw + 3145728;       // (B,H,D,N)
  unsigned short* pkw = vtw + 3145728;      // 6*768*64
  unsigned short* pqw = pkw + 294912;       // (pre-scaled)
  unsigned short* aow = pqw + 294912;       // 8192*384 bf16
  unsigned short* xb  = aow + 3145728;      // 8192*384 bf16
  unsigned short* reb = xb + 3145728;       // 768*384 bf16  (end ~41.3 MB)

  prep_all<<<dim3(1896), 256, 0, stream>>>(x, re, Wq, Wk, Wv, Wpk, Wpq, Wo,
                                           xb, reb, Wt);
  proj_all<<<dim3(128, 4), 256, 0, stream>>>(xb, reb, Wt, bq, bk, bv, bpk, bpq,
                                             qw, kw, vtw, pkw, pqw);
  attn_fused<<<dim3(16, 48), 256, 0, stream>>>(qw, kw, vtw, pkw, pqw, aow);
  out_gemm<<<dim3(128), 256, 0, stream>>>(aow, Wt + 5 * 147456, bo, out);
}

// Round 21
// 257.753 us; speedup vs baseline: 1.0227x; 1.0227x over previous
//
#include <hip/hip_runtime.h>
#include <math.h>

typedef __attribute__((ext_vector_type(8))) short short8;
typedef __attribute__((ext_vector_type(4))) float v4f;
typedef __attribute__((ext_vector_type(4))) unsigned short us4;

#define INV_SCALE 0.07216878364870322f  // 1/sqrt(64*3)

__device__ __forceinline__ unsigned short f2bf(float f) {
  unsigned u = __builtin_bit_cast(unsigned, f);
  u = (u + 0x7FFFu + ((u >> 16) & 1u)) >> 16;  // RNE
  return (unsigned short)u;
}
__device__ __forceinline__ float bf2f(unsigned short h) {
  unsigned u = ((unsigned)h) << 16;
  return __builtin_bit_cast(float, u);
}

enum { OM_PLAIN = 0, OM_Q = 1, OM_K = 2, OM_VT = 3, OM_PK = 4, OM_PQ = 5 };

// -----------------------------------------------------------------------------
// ROUND-21: REVERT to R16 EXACTLY (best measured 257.3 us). R20's NP=6 A/B
// came back +6 us (408 blocks cover only 53% of CUs during proj; idle CUs
// cost more than the saved restage). NP=3 with 816 spread blocks wins.
// Final config: prep_all (cvt+transpose merged) + proj_all NP=3 (128,10) +
// attn_fused (R8 verbatim) + out_gemm NP=3 (128,2).
// -----------------------------------------------------------------------------
// prep_all grid: 1896 blocks. bid < 1680: x/re -> bf16 (8 elems/thread).
// bid >= 1680: weight transpose tile (6 mats x 36 tiles).
__global__ __launch_bounds__(256) void prep_all(
    const float* __restrict__ x, const float* __restrict__ re,
    const float* __restrict__ Wq, const float* __restrict__ Wk,
    const float* __restrict__ Wv, const float* __restrict__ Wpk,
    const float* __restrict__ Wpq, const float* __restrict__ Wo,
    unsigned short* __restrict__ xb, unsigned short* __restrict__ reb,
    unsigned short* __restrict__ Wt) {
  __shared__ unsigned short Ts[64][68];
  const int bid = blockIdx.x;
  const int t = threadIdx.x;
  if (bid < 1680) {
    size_t idx = ((size_t)bid * 256 + t) * 8;
    const float* src;
    unsigned short* dst;
    if (idx < 3145728) {
      src = x + idx; dst = xb + idx;
    } else {
      size_t r = idx - 3145728;
      if (r >= 294912) return;
      src = re + r; dst = reb + r;
    }
    float4 u0 = *(const float4*)src;
    float4 u1 = *(const float4*)(src + 4);
    short8 v;
    v[0] = (short)f2bf(u0.x); v[1] = (short)f2bf(u0.y);
    v[2] = (short)f2bf(u0.z); v[3] = (short)f2bf(u0.w);
    v[4] = (short)f2bf(u1.x); v[5] = (short)f2bf(u1.y);
    v[6] = (short)f2bf(u1.z); v[7] = (short)f2bf(u1.w);
    *(short8*)dst = v;
    return;
  }
  // weight transpose: 384x384 fp32 [k][n] -> bf16 [n][k]
  const int wb = bid - 1680;
  const int mat = wb / 36, rem = wb % 36;
  const float* W = mat == 0 ? Wq : mat == 1 ? Wk : mat == 2 ? Wv
                 : mat == 3 ? Wpk : mat == 4 ? Wpq : Wo;
  const int tk = (rem % 6) * 64, tn = (rem / 6) * 64;
#pragma unroll
  for (int it = 0; it < 4; ++it) {
    int r = (t >> 4) + it * 16, c = (t & 15) * 4;
    float4 v = *(const float4*)(W + (size_t)(tk + r) * 384 + tn + c);
    us4 p = {f2bf(v.x), f2bf(v.y), f2bf(v.z), f2bf(v.w)};
    *(us4*)&Ts[r][c] = p;
  }
  __syncthreads();
  unsigned short* outp = Wt + (size_t)mat * 147456;
#pragma unroll
  for (int it = 0; it < 2; ++it) {
    int n = (t >> 3) + it * 32, kc = (t & 7) * 8;
    unsigned short tmp[8];
#pragma unroll
    for (int j = 0; j < 8; ++j) tmp[j] = Ts[kc + j][n];
    *(short8*)(outp + (size_t)(tn + n) * 384 + tk + kc) = *(short8*)tmp;
  }
}

// -----------------------------------------------------------------------------
// GEMM body (R9 panel-loop): A-frags (bf16) loaded ONCE per block into
// registers; loop NP n-panels restaging only B (L2-resident Wt).
// -----------------------------------------------------------------------------
template <int OMODE, int NP>
__device__ __forceinline__ void pgemm_body(
    const unsigned short* __restrict__ A, const unsigned short* __restrict__ Bt,
    const float* __restrict__ bias, void* __restrict__ out,
    int m0, int ng0, float scale, unsigned short (*Bs)[392]) {
  const int t = threadIdx.x;
  const int lane = t & 63, w = t >> 6, li = lane & 15, quad = lane >> 4;
  const int row = m0 + w * 16 + li;
  const int sr = t >> 2, scq = (t & 3) * 96;

#pragma unroll
  for (int i = 0; i < 12; ++i)
    *(short8*)&Bs[sr][scq + i * 8] =
        *(const short8*)(Bt + (size_t)(ng0 * 64 + sr) * 384 + scq + i * 8);

  short8 afr[12];
#pragma unroll
  for (int kk = 0; kk < 12; ++kk)
    afr[kk] = *(const short8*)(A + (size_t)row * 384 + kk * 32 + quad * 8);

#pragma unroll
  for (int pp = 0; pp < NP; ++pp) {
    __syncthreads();  // stage of panel pp visible
    v4f acc[4] = {};
#pragma unroll
    for (int kk = 0; kk < 12; ++kk) {
#pragma unroll
      for (int nt = 0; nt < 4; ++nt) {
        short8 bf = *(const short8*)&Bs[nt * 16 + li][kk * 32 + quad * 8];
        acc[nt] = __builtin_amdgcn_mfma_f32_16x16x32_bf16(afr[kk], bf, acc[nt], 0, 0, 0);
      }
    }
    __syncthreads();  // all Bs reads done; free for restage
    if (pp + 1 < NP) {
#pragma unroll
      for (int i = 0; i < 12; ++i)
        *(short8*)&Bs[sr][scq + i * 8] =
            *(const short8*)(Bt + (size_t)((ng0 + pp + 1) * 64 + sr) * 384 + scq + i * 8);
    }
    const int n0 = (ng0 + pp) * 64;
#pragma unroll
    for (int nt = 0; nt < 4; ++nt) {
      int col = n0 + nt * 16 + li;
      float bv = bias[col];
      int h = col >> 6, d = col & 63;
#pragma unroll
      for (int i = 0; i < 4; ++i) {
        int orow = m0 + w * 16 + quad * 4 + i;
        float val = (acc[nt][i] + bv) * scale;
        if constexpr (OMODE == OM_PLAIN) {
          ((float*)out)[(size_t)orow * 384 + col] = val;
        } else if constexpr (OMODE == OM_Q || OMODE == OM_K) {
          int b = orow >> 10, n = orow & 1023;
          ((unsigned short*)out)[((size_t)(b * 6 + h) << 16) + (n << 6) + d] = f2bf(val);
        } else if constexpr (OMODE == OM_VT) {
          int b = orow >> 10, n = orow & 1023;
          ((unsigned short*)out)[((size_t)(b * 6 + h) << 16) + (d << 10) + n] = f2bf(val);
        } else {  // OM_PK / OM_PQ: [h][p][d]
          ((unsigned short*)out)[(size_t)h * 49152 + (size_t)orow * 64 + d] = f2bf(val);
        }
      }
    }
  }
}

// Grid (128, 10): y<6 -> which=y>>1 (q/k/v), ng0=(y&1)*3, M=8192;
// y>=6 -> p=y-6: which=3+(p>>1) (pk/pq), ng0=(p&1)*3, M=768 (x<12).
__global__ __launch_bounds__(256, 3) void proj_all(
    const unsigned short* __restrict__ xb, const unsigned short* __restrict__ reb,
    const unsigned short* __restrict__ Wt,
    const float* __restrict__ bq, const float* __restrict__ bk,
    const float* __restrict__ bv, const float* __restrict__ bpk,
    const float* __restrict__ bpq,
    unsigned short* __restrict__ qw, unsigned short* __restrict__ kw,
    unsigned short* __restrict__ vtw, unsigned short* __restrict__ pkw,
    unsigned short* __restrict__ pqw) {
  __shared__ __align__(16) unsigned short Bs[64][392];
  const int y = blockIdx.y;
  const int m0 = blockIdx.x * 64;
  int which, ng0;
  if (y < 6) {
    which = y >> 1; ng0 = (y & 1) * 3;
  } else {
    int p = y - 6;
    which = 3 + (p >> 1); ng0 = (p & 1) * 3;
    if (m0 >= 768) return;
  }
  const unsigned short* A = which < 3 ? xb : reb;
  const unsigned short* Bt = Wt + (size_t)which * 147456;
  switch (which) {
    case 0: pgemm_body<OM_Q, 3>(A, Bt, bq,  qw,  m0, ng0, INV_SCALE, Bs); break;
    case 1: pgemm_body<OM_K, 3>(A, Bt, bk,  kw,  m0, ng0, 1.f, Bs); break;
    case 2: pgemm_body<OM_VT,3>(A, Bt, bv,  vtw, m0, ng0, 1.f, Bs); break;
    case 3: pgemm_body<OM_PK,3>(A, Bt, bpk, pkw, m0, ng0, 1.f, Bs); break;
    default: pgemm_body<OM_PQ,3>(A, Bt, bpq, pqw, m0, ng0, INV_SCALE, Bs); break;
  }
}

// Grid (128, 2): ng0 = y*3, 3 panels per block; A (aow bf16) read 2x not 6x.
__global__ __launch_bounds__(256, 3) void out_gemm(
    const unsigned short* __restrict__ ao, const unsigned short* __restrict__ Bt,
    const float* __restrict__ bo, float* __restrict__ out) {
  __shared__ __align__(16) unsigned short Bs[64][392];
  pgemm_body<OM_PLAIN, 3>(ao, Bt, bo, out,
                          blockIdx.x * 64, blockIdx.y * 3, 1.f, Bs);
}

// -----------------------------------------------------------------------------
// Fused disentangled attention — ROUND-8 KERNEL VERBATIM (best measured:
// 139.4-141.4 us, FETCH 14.6 MB). XCD working-set swizzle (validated: FETCH
// 60->14.6 MB) + T14 stage split on the 146 us ROUND-4 structure (ASTR=72,
// LDS band staging, 4 barriers, register-lean). Do not touch.
// -----------------------------------------------------------------------------
#define ASTR 72  // LDS row stride in shorts (144 B): 16B-aligned, 2-way-free banks

__global__ __launch_bounds__(256, 3) void attn_fused(
    const unsigned short* __restrict__ q, const unsigned short* __restrict__ k,
    const unsigned short* __restrict__ vt, const unsigned short* __restrict__ pk,
    const unsigned short* __restrict__ pq, unsigned short* __restrict__ ao) {
  __shared__ __align__(16) unsigned short band1[128][ASTR];  // pk band, then T1^T
  __shared__ __align__(16) unsigned short band2[128][ASTR];  // pq band, then T2^T
  __shared__ __align__(16) unsigned short Ps[64][ASTR];

  // XCD working-set remap: flat id -> (bh, n0) so each XCD owns 6 bh.
  const int f = blockIdx.x + (blockIdx.y << 4);  // hw linear id, 0..767
  const int g = f & 7, s = f >> 3;               // XCD group, slot
  const int bh = g * 6 + (s >> 4);
  const int n0 = (s & 15) * 64;
  const int h = bh % 6, b = bh / 6;
  const int t = threadIdx.x;
  const int lane = t & 63, w = t >> 6;
  const int li = lane & 15, quad = lane >> 4;

  const unsigned short* qb = q + ((size_t)bh << 16);
  const unsigned short* kb = k + ((size_t)bh << 16);
  const unsigned short* vb = vt + ((size_t)bh << 16);
  const unsigned short* pkh = pk + (size_t)h * 49152;
  const unsigned short* pqh = pq + (size_t)h * 49152;

  // q A-frags: loaded once (q pre-scaled by INV_SCALE)
  short8 aq0 = *(const short8*)(qb + (size_t)(n0 + w * 16 + li) * 64 + quad * 8);
  short8 aq1 = *(const short8*)(qb + (size_t)(n0 + w * 16 + li) * 64 + 32 + quad * 8);

  float l_part[4] = {0.f, 0.f, 0.f, 0.f};
  v4f o[4] = {};

  // T14 stage split: per-thread staging slice (row sr, 32-short quarter sc).
  const int sr = t >> 1, sc = (t & 1) * 32;
  short8 st1[4], st2[4];
  {
    int src = n0 - 0 - 63 + 384 + sr;
    src = src < 0 ? 0 : (src > 767 ? 767 : src);
    const unsigned short* p1 = pkh + (size_t)src * 64 + sc;
    const unsigned short* p2 = pqh + (size_t)src * 64 + sc;
#pragma unroll
    for (int ss = 0; ss < 4; ++ss) {
      st1[ss] = *(const short8*)(p1 + ss * 8);
      st2[ss] = *(const short8*)(p2 + ss * 8);
    }
  }

  for (int j0 = 0; j0 < 1024; j0 += 64) {
    __syncthreads();  // S0: prev gather reads done; band buffers free
    // ---- write pre-fetched pos bands to LDS ----
#pragma unroll
    for (int ss = 0; ss < 4; ++ss) {
      *(short8*)&band1[sr][sc + ss * 8] = st1[ss];
      *(short8*)&band2[sr][sc + ss * 8] = st2[ss];
    }
    __syncthreads();  // S1: bands visible

    // ---- issue next tile's stage loads (consumed at next S0) ----
    {
      int src = n0 - (j0 + 64) - 63 + 384 + sr;  // last iter: clamped, unused
      src = src < 0 ? 0 : (src > 767 ? 767 : src);
      const unsigned short* p1 = pkh + (size_t)src * 64 + sc;
      const unsigned short* p2 = pqh + (size_t)src * 64 + sc;
#pragma unroll
      for (int ss = 0; ss < 4; ++ss) {
        st1[ss] = *(const short8*)(p1 + ss * 8);
        st2[ss] = *(const short8*)(p2 + ss * 8);
      }
    }

    // k A-frags for T2 (rows j0 + w*16 + li)
    short8 ak0 = *(const short8*)(kb + (size_t)(j0 + w * 16 + li) * 64 + quad * 8);
    short8 ak1 = *(const short8*)(kb + (size_t)(j0 + w * 16 + li) * 64 + 32 + quad * 8);

    // ---- T1 = q' @ pkband^T, T2 = k @ pq'band^T (B-frags from LDS) ----
    v4f t1a[8] = {}, t2a[8] = {};
#pragma unroll
    for (int ct = 0; ct < 8; ++ct) {
      short8 b10 = *(const short8*)&band1[ct * 16 + li][quad * 8];
      short8 b11 = *(const short8*)&band1[ct * 16 + li][32 + quad * 8];
      t1a[ct] = __builtin_amdgcn_mfma_f32_16x16x32_bf16(aq0, b10, t1a[ct], 0, 0, 0);
      t1a[ct] = __builtin_amdgcn_mfma_f32_16x16x32_bf16(aq1, b11, t1a[ct], 0, 0, 0);
      short8 b20 = *(const short8*)&band2[ct * 16 + li][quad * 8];
      short8 b21 = *(const short8*)&band2[ct * 16 + li][32 + quad * 8];
      t2a[ct] = __builtin_amdgcn_mfma_f32_16x16x32_bf16(ak0, b20, t2a[ct], 0, 0, 0);
      t2a[ct] = __builtin_amdgcn_mfma_f32_16x16x32_bf16(ak1, b21, t2a[ct], 0, 0, 0);
    }
    __syncthreads();  // S2: all band B-frag reads complete before overwrite

    // ---- write T1^T/T2^T into the (dead) band buffers ----
#pragma unroll
    for (int ct = 0; ct < 8; ++ct) {
      us4 p1 = {f2bf(t1a[ct][0]), f2bf(t1a[ct][1]), f2bf(t1a[ct][2]), f2bf(t1a[ct][3])};
      us4 p2 = {f2bf(t2a[ct][0]), f2bf(t2a[ct][1]), f2bf(t2a[ct][2]), f2bf(t2a[ct][3])};
      *(us4*)&band1[ct * 16 + li][w * 16 + quad * 4] = p1;
      *(us4*)&band2[ct * 16 + li][w * 16 + quad * 4] = p2;
    }
    // ---- S_qk (B-frags = k rows direct from global/L1) ----
    v4f sqk[4] = {};
#pragma unroll
    for (int nt = 0; nt < 4; ++nt) {
      short8 b0 = *(const short8*)(kb + (size_t)(j0 + nt * 16 + li) * 64 + quad * 8);
      short8 b1 = *(const short8*)(kb + (size_t)(j0 + nt * 16 + li) * 64 + 32 + quad * 8);
      sqk[nt] = __builtin_amdgcn_mfma_f32_16x16x32_bf16(aq0, b0, sqk[nt], 0, 0, 0);
      sqk[nt] = __builtin_amdgcn_mfma_f32_16x16x32_bf16(aq1, b1, sqk[nt], 0, 0, 0);
    }
    __syncthreads();  // S3: T^T visible cross-wave

    // ---- gather + exp (scale pre-folded) + Ps ----
#pragma unroll
    for (int nt = 0; nt < 4; ++nt) {
      int jl = nt * 16 + li;
#pragma unroll
      for (int i = 0; i < 4; ++i) {
        int nl = w * 16 + quad * 4 + i;
        int r = nl - jl + 63;
        float s2 = sqk[nt][i] + bf2f(band1[r][nl]) + bf2f(band2[r][jl]);
        float p = __expf(s2);
        l_part[i] += p;
        Ps[nl][jl] = f2bf(p);
      }
    }
    // ---- PV (A-frag Ps: same-wave rows; B-frag vt direct from global) ----
#pragma unroll
    for (int kst = 0; kst < 2; ++kst) {
      short8 ap = *(const short8*)&Ps[w * 16 + li][kst * 32 + quad * 8];
#pragma unroll
      for (int nt = 0; nt < 4; ++nt) {
        short8 bv2 = *(const short8*)(vb + (size_t)(nt * 16 + li) * 1024 + j0 + kst * 32 + quad * 8);
        o[nt] = __builtin_amdgcn_mfma_f32_16x16x32_bf16(ap, bv2, o[nt], 0, 0, 0);
      }
    }
  }

  // final: reduce l across the 16 col-lanes, normalize, store (B,N,C) bf16
#pragma unroll
  for (int i = 0; i < 4; ++i) {
    float l = l_part[i];
    l += __shfl_xor(l, 1);
    l += __shfl_xor(l, 2);
    l += __shfl_xor(l, 4);
    l += __shfl_xor(l, 8);
    float inv_l = 1.f / l;
    int nl = w * 16 + quad * 4 + i;
#pragma unroll
    for (int nt = 0; nt < 4; ++nt)
      ao[((size_t)(b * 1024 + n0 + nl)) * 384 + h * 64 + nt * 16 + li] =
          f2bf(o[nt][i] * inv_l);
  }
}

// -----------------------------------------------------------------------------
extern "C" void kernel_launch(void* const* d_in, const int* in_sizes, int n_in,
                              void* d_out, int out_size, void* d_ws,
                              size_t ws_size, hipStream_t stream) {
  const float* x   = (const float*)d_in[0];
  const float* re  = (const float*)d_in[2];
  const float* Wq  = (const float*)d_in[3];
  const float* bq  = (const float*)d_in[4];
  const float* Wk  = (const float*)d_in[5];
  const float* bk  = (const float*)d_in[6];
  const float* Wv  = (const float*)d_in[7];
  const float* bv  = (const float*)d_in[8];
  const float* Wpk = (const float*)d_in[9];
  const float* bpk = (const float*)d_in[10];
  const float* Wpq = (const float*)d_in[11];
  const float* bpq = (const float*)d_in[12];
  const float* Wo  = (const float*)d_in[13];
  const float* bo  = (const float*)d_in[14];
  float* out = (float*)d_out;

  unsigned short* ws = (unsigned short*)d_ws;
  unsigned short* Wt  = ws;                 // 6*384*384
  unsigned short* qw  = Wt + 884736;        // 48*1024*64 (pre-scaled)
  unsigned short* kw  = qw + 3145728;
  unsigned short* vtw = kw + 3145728;       // (B,H,D,N)
  unsigned short* pkw = vtw + 3145728;      // 6*768*64
  unsigned short* pqw = pkw + 294912;       // (pre-scaled)
  unsigned short* aow = pqw + 294912;       // 8192*384 bf16
  unsigned short* xb  = aow + 3145728;      // 8192*384 bf16
  unsigned short* reb = xb + 3145728;       // 768*384 bf16  (end ~41.3 MB)

  prep_all<<<dim3(1896), 256, 0, stream>>>(x, re, Wq, Wk, Wv, Wpk, Wpq, Wo,
                                           xb, reb, Wt);
  proj_all<<<dim3(128, 10), 256, 0, stream>>>(xb, reb, Wt, bq, bk, bv, bpk, bpq,
                                              qw, kw, vtw, pkw, pqw);
  attn_fused<<<dim3(16, 48), 256, 0, stream>>>(qw, kw, vtw, pkw, pqw, aow);
  out_gemm<<<dim3(128, 2), 256, 0, stream>>>(aow, Wt + 5 * 147456, bo, out);
}